// Round 2
// baseline (245.317 us; speedup 1.0000x reference)
//
#include <hip/hip_runtime.h>

#define N_RES 2048
#define BATCH 16
#define LMAX  13
#define NSLOT 14          // LMAX atm slots + 1 amn slot
#define DV    64
#define VSTR  68          // padded v-stride per (m,l) row: keeps 16B alignment (68*4=272=16*17)
                          // and skews banks for the staging writes (stride 68 -> +4 banks/row)

__device__ __constant__ int RES_LEN_D[20] = {3,4,5,5,6,6,6,7,7,7,7,7,8,8,8,9,10,10,11,13};

__global__ __launch_bounds__(256, 3)
void posmix_kernel(const float* __restrict__ pos_atm,
                   const float* __restrict__ pos_amn,
                   const float* __restrict__ W_amn,
                   const float* __restrict__ W_atm,
                   const int*   __restrict__ seq,
                   float* __restrict__ out_atm,
                   float* __restrict__ out_amn,
                   int atoms)
{
  const int i   = blockIdx.x;
  const int tid = threadIdx.x;
  const int t   = seq[i];
  const int L   = RES_LEN_D[t];

  // w_lds: [slot m][l][v] with padded v-stride VSTR; 14*13*68*4 = 49,504 B
  __shared__ __align__(16) float w_lds[NSLOT * LMAX * VSTR];
  // diff_lds: [b][40] packed (l*3+d), zero past 3L; 16*40*4 = 2,560 B
  __shared__ __align__(16) float diff_lds[BATCH * 40];

  // ---- start_i = sum of lens of residues < i (alias diff_lds as scratch) ----
  int* red = (int*)diff_lds;
  {
    int s = 0;
    int base = tid * 8;
    #pragma unroll
    for (int k = 0; k < 8; ++k) {
      int r = base + k;
      if (r < i) s += RES_LEN_D[seq[r]];
    }
    red[tid] = s;
  }
  __syncthreads();
  #pragma unroll
  for (int off = 128; off > 0; off >>= 1) {
    if (tid < off) red[tid] += red[tid + off];
    __syncthreads();
  }
  const int start = red[0];
  __syncthreads();   // release scratch alias before diff staging

  // ---- stage W transposed: w_lds[(m*13+l)*VSTR + v] = W[m][v][l] ----
  // read is coalesced (l fastest); write bank = (l*68+v)%32 -> ~2-way max
  {
    const float* Wt = W_atm + (size_t)t * (LMAX * DV * LMAX);
    const float* Wa = W_amn + (size_t)t * (DV * LMAX);
    const int total = (L + 1) * (DV * LMAX);
    for (int g = tid; g < total; g += 256) {
      int m = g / (DV * LMAX);
      int r = g - m * (DV * LMAX);      // r = v*13 + l
      int v = r / LMAX;
      int l = r - v * LMAX;
      const float* src = (m < L) ? (Wt + (size_t)m * (DV * LMAX)) : Wa;
      w_lds[(m * LMAX + l) * VSTR + v] = src[r];
    }
  }

  // ---- stage diffs packed: diff_lds[b*40 + l*3 + d], zero for l >= L ----
  if (tid < BATCH * LMAX) {
    int b = tid / LMAX;
    int l = tid - b * LMAX;
    float dx = 0.f, dy = 0.f, dz = 0.f;
    if (l < L) {
      const float* pa = pos_atm + ((size_t)b * atoms + (size_t)(start + l)) * 3;
      const float* pm = pos_amn + ((size_t)b * N_RES + i) * 3;
      dx = pa[0] - pm[0];
      dy = pa[1] - pm[1];
      dz = pa[2] - pm[2];
    }
    float* dd = diff_lds + b * 40 + l * 3;
    dd[0] = dx; dd[1] = dy; dd[2] = dz;
  }
  if (tid < BATCH) diff_lds[tid * 40 + 39] = 0.f;   // pad element
  __syncthreads();

  // ---- compute: thread = (b = tid>>4, va = tid&15); iteration = slot m ----
  const int b  = tid >> 4;
  const int va = tid & 15;

  // pull this thread's diff row into registers once (reused for all m slots)
  float df[40] __attribute__((aligned(16)));
  {
    const float4* s4 = (const float4*)(diff_lds + b * 40);
    float4* d4 = (float4*)df;
    #pragma unroll
    for (int k = 0; k < 10; ++k) d4[k] = s4[k];
  }

  const float* wbase = w_lds + 4 * va;

  for (int m = 0; m <= L; ++m) {
    const float* wr = wbase + (m * LMAX) * VSTR;

    float acc[12];
    #pragma unroll
    for (int j = 0; j < 12; ++j) acc[j] = 0.f;

    #pragma unroll
    for (int l = 0; l < LMAX; ++l) {        // full 13: diff is zero-padded past L
      float4 w = *(const float4*)(wr + l * VSTR);   // one ds_read_b128
      float dx = df[3*l + 0], dy = df[3*l + 1], dz = df[3*l + 2];
      acc[0]  += w.x * dx; acc[1]  += w.x * dy; acc[2]  += w.x * dz;
      acc[3]  += w.y * dx; acc[4]  += w.y * dy; acc[5]  += w.y * dz;
      acc[6]  += w.z * dx; acc[7]  += w.z * dy; acc[8]  += w.z * dz;
      acc[9]  += w.w * dx; acc[10] += w.w * dy; acc[11] += w.w * dz;
    }

    // 12 contiguous output floats at channel offset va*12 (16B aligned)
    float* dst = (m < L)
      ? out_atm + ((size_t)b * atoms + (size_t)(start + m)) * 192 + va * 12
      : out_amn + ((size_t)b * N_RES + i) * 192 + va * 12;
    *(float4*)(dst + 0) = make_float4(acc[0], acc[1],  acc[2],  acc[3]);
    *(float4*)(dst + 4) = make_float4(acc[4], acc[5],  acc[6],  acc[7]);
    *(float4*)(dst + 8) = make_float4(acc[8], acc[9],  acc[10], acc[11]);
  }
}

extern "C" void kernel_launch(void* const* d_in, const int* in_sizes, int n_in,
                              void* d_out, int out_size, void* d_ws, size_t ws_size,
                              hipStream_t stream) {
  const float* pos_atm = (const float*)d_in[0];
  const float* pos_amn = (const float*)d_in[1];
  const float* W_amn   = (const float*)d_in[2];
  const float* W_atm   = (const float*)d_in[3];
  const int*   seq     = (const int*)d_in[4];

  const int atoms = in_sizes[0] / (BATCH * 3);   // 15036
  float* out_atm = (float*)d_out;
  float* out_amn = out_atm + (size_t)BATCH * atoms * DV * 3;

  posmix_kernel<<<N_RES, 256, 0, stream>>>(pos_atm, pos_amn, W_amn, W_atm, seq,
                                           out_atm, out_amn, atoms);
}